// Round 18
// baseline (220.307 us; speedup 1.0000x reference)
//
#include <hip/hip_runtime.h>
#include <hip/hip_bf16.h>

#define LL 1024
#define HID 768
#define NH 12
#define HD 64
#define KAUG 192   // 64 (q/8 or k) + 64 e1 + 64 e2
#define NBH 48     // B*NH

typedef unsigned int u32;
typedef unsigned short u16;
typedef __bf16 bf16_t;
typedef bf16_t bf16x8 __attribute__((ext_vector_type(8)));
typedef _Float16 f16x4 __attribute__((ext_vector_type(4)));
typedef float f32x4 __attribute__((ext_vector_type(4)));
typedef u32 u32x4 __attribute__((ext_vector_type(4)));

__device__ __forceinline__ u16 f2b(float f) {
    union { float f; u32 u; } v; v.f = f;
    u32 r = v.u + 0x7fffu + ((v.u >> 16) & 1u);
    return (u16)(r >> 16);
}
__device__ __forceinline__ u16 f2h(float f) {
    _Float16 h = (_Float16)f;
    return __builtin_bit_cast(u16, h);
}
__device__ __forceinline__ bf16x8 load8s(const u16* p) {  // LDS/global, 16B aligned
    return __builtin_bit_cast(bf16x8, *reinterpret_cast<const u32x4*>(p));
}
__device__ __forceinline__ f16x4 load4h(const u16* p) {   // LDS, 8B aligned
    return __builtin_bit_cast(f16x4, *reinterpret_cast<const unsigned long long*>(p));
}
__device__ __forceinline__ void cvt4_store_v(u16* dst, float4 f) {
    ushort4 o;
    o.x = f2b(f.x); o.y = f2b(f.y); o.z = f2b(f.z); o.w = f2b(f.w);
    *reinterpret_cast<ushort4*>(dst) = o;
}

// ---------------------------------------------------------------- A0: f32 -> bf16 cvt (hs [0,1536) | W [1536,2400))
__global__ __launch_bounds__(256) void k_pre(const float* __restrict__ hs,
                                             const float* __restrict__ Wq, const float* __restrict__ Wk,
                                             const float* __restrict__ Wv,
                                             u16* __restrict__ hs16, u16* __restrict__ w16) {
    int bx = blockIdx.x;
    const float* src; u16* dst; int base;
    if (bx < 1536) { src = hs; dst = hs16; base = bx; }
    else {
        int w = bx - 1536;               // 0..863
        int which = w / 288;             // 0=q 1=k 2=v
        src = (which == 0) ? Wq : (which == 1) ? Wk : Wv;
        dst = w16 + (size_t)which * 768 * 768;
        base = w - which * 288;
    }
    int idx = (base * 256 + threadIdx.x) * 8;
    float4 a = *reinterpret_cast<const float4*>(&src[idx]);
    float4 b = *reinterpret_cast<const float4*>(&src[idx + 4]);
    cvt4_store_v(&dst[idx], a);
    cvt4_store_v(&dst[idx + 4], b);
}

// ---------------------------------------------------------------- A2+A3+A1 fused: QKV + walk-PE + dist-pack
// segments: [0,576) qkv MFMA blocks (dispatch first) | [576,4672) pe |
// [4672,6720) dist pack. All outputs disjoint; pe/pack soak up CUs while
// qkv blocks wait on memory (r14: fusion gained ~32us).
__global__ __launch_bounds__(256) void k_qkvpe(const u16* __restrict__ hs16,
                                               const u16* __restrict__ w16,
                                               const float* __restrict__ bq, const float* __restrict__ bk,
                                               const float* __restrict__ bv,
                                               const int* __restrict__ rw, const int* __restrict__ arw,
                                               const float* __restrict__ node_emb,
                                               const int* __restrict__ distance,
                                               u16* __restrict__ Qa, u16* __restrict__ Ka,
                                               u16* __restrict__ Vt, u16* __restrict__ distu) {
    __shared__ __align__(16) u16 smem[18432];
    int lin = blockIdx.x;
    int tid = threadIdx.x;
    if (lin < 576) {
        // ---------------- QKV path (XCD-affine: xcd owns m-tiles [4x,4x+4) x all nt)
        u16* a_s = smem;                 // [row][col] stride 72
        u16* b_s = smem + 9216;
        int xcd = lin & 7, idx = lin >> 3;          // idx 0..71
        int mt = xcd * 4 + (idx & 3);               // 0..31
        int nt = idx >> 2;                          // 0..17
        int m0 = mt * 128;
        int which = nt / 6;                  // 0=q 1=k 2=v
        int n0w = (nt % 6) * 128;
        const u16* W = w16 + (size_t)which * 768 * 768;
        const float* bias = (which == 0) ? bq : (which == 1) ? bk : bv;
        int wave = tid >> 6, lane = tid & 63, l15 = lane & 15, qd = lane >> 4;
        int wm = wave >> 1, wn = wave & 1;
        int srow = tid >> 3, scol = (tid & 7) * 8;

        f32x4 acc[4][4];
        for (int i = 0; i < 4; i++)
            for (int j = 0; j < 4; j++) acc[i][j] = f32x4{0.f, 0.f, 0.f, 0.f};

        u32x4 pa[4], pb[4];
#pragma unroll
        for (int it = 0; it < 4; it++) {
            int row = srow + it * 32;
            pa[it] = *reinterpret_cast<const u32x4*>(&hs16[(size_t)(m0 + row) * 768 + scol]);
            pb[it] = *reinterpret_cast<const u32x4*>(&W[(size_t)(n0w + row) * 768 + scol]);
        }
        for (int k0 = 0; k0 < 768; k0 += 64) {
            __syncthreads();
#pragma unroll
            for (int it = 0; it < 4; it++) {
                int row = srow + it * 32;
                *reinterpret_cast<u32x4*>(&a_s[row * 72 + scol]) = pa[it];
                *reinterpret_cast<u32x4*>(&b_s[row * 72 + scol]) = pb[it];
            }
            __syncthreads();
            if (k0 < 704) {
                int k1 = k0 + 64;
#pragma unroll
                for (int it = 0; it < 4; it++) {
                    int row = srow + it * 32;
                    pa[it] = *reinterpret_cast<const u32x4*>(&hs16[(size_t)(m0 + row) * 768 + k1 + scol]);
                    pb[it] = *reinterpret_cast<const u32x4*>(&W[(size_t)(n0w + row) * 768 + k1 + scol]);
                }
            }
            for (int kk = 0; kk < 2; kk++) {
                bf16x8 af[4], bf[4];
                for (int i = 0; i < 4; i++) af[i] = load8s(&a_s[(wm * 64 + i * 16 + l15) * 72 + kk * 32 + qd * 8]);
                for (int j = 0; j < 4; j++) bf[j] = load8s(&b_s[(wn * 64 + j * 16 + l15) * 72 + kk * 32 + qd * 8]);
                for (int i = 0; i < 4; i++)
                    for (int j = 0; j < 4; j++)
                        acc[i][j] = __builtin_amdgcn_mfma_f32_16x16x32_bf16(af[i], bf[j], acc[i][j], 0, 0, 0);
            }
        }
        __syncthreads();
        int b = m0 >> 10, l0b = m0 & 1023;
        if (which != 2) {
            float qscale = (which == 0) ? 0.125f : 1.0f;
            for (int i = 0; i < 4; i++) {
                int m_loc = wm * 64 + i * 16 + qd * 4;
                for (int j = 0; j < 4; j++) {
                    int n_loc = wn * 64 + j * 16 + l15;
                    float bv_ = bias[n0w + n_loc];
                    for (int r = 0; r < 4; r++)
                        smem[(m_loc + r) * 136 + n_loc] = f2b((acc[i][j][r] + bv_) * qscale);
                }
            }
            __syncthreads();
            u16* dstbuf = (which == 0) ? Qa : Ka;
            for (int it = 0; it < 8; it++) {
                int c = tid + it * 256;
                int row = c >> 4, col = (c & 15) * 8;
                u32x4 w = *reinterpret_cast<u32x4*>(&smem[row * 136 + col]);
                int nn = n0w + col;
                int h = nn >> 6, d = nn & 63;
                size_t dst = ((size_t)(b * NH + h) * LL + (l0b + row)) * KAUG + d;
                *reinterpret_cast<u32x4*>(&dstbuf[dst]) = w;
            }
        } else {
            // V stored as FP16 (feeds the 16x16x16 f16 PV MFMA in k_attn)
            for (int i = 0; i < 4; i++) {
                int m_loc = wm * 64 + i * 16 + qd * 4;
                for (int j = 0; j < 4; j++) {
                    int n_loc = wn * 64 + j * 16 + l15;
                    float bv_ = bias[n0w + n_loc];
                    for (int r = 0; r < 4; r++)
                        smem[n_loc * 136 + (m_loc + r)] = f2h(acc[i][j][r] + bv_);
                }
            }
            __syncthreads();
            for (int it = 0; it < 8; it++) {
                int c = tid + it * 256;
                int n = c >> 4, m_off = (c & 15) * 8;
                u32x4 w = *reinterpret_cast<u32x4*>(&smem[n * 136 + m_off]);
                int nn = n0w + n;
                int h = nn >> 6, d = nn & 63;
                size_t dst = ((size_t)(b * NH + h) * HD + d) * LL + (l0b + m_off);
                *reinterpret_cast<u32x4*>(&Vt[dst]) = w;
            }
        }
    } else if (lin < 4672) {
        // ---------------- PE path: histogram + counts @ node_emb
        int m = lin - 576;                   // b*L + l, 0..4095
        int* hist = (int*)smem;              // 64 ints @ byte 0
        float* c1 = (float*)(smem + 128);    // 32 f @ byte 256
        float* c2 = (float*)(smem + 192);    // 32 f @ byte 384
        u16* pe_s = smem + 256;              // 1536 u16 @ byte 512
        int t = tid;
        if (t < 64) hist[t] = 0;
        __syncthreads();
        if (t < 128) atomicAdd(&hist[rw[m * 128 + t] & 31], 1);
        else         atomicAdd(&hist[32 + (arw[m * 128 + (t - 128)] & 31)], 1);
        __syncthreads();
        if (t < 64) {
            if (t < 32) c1[t] = (float)hist[t];
            else        c2[t - 32] = (float)hist[t];
        }
        __syncthreads();
        for (int c = t; c < 768; c += 256) {
            float s1 = 0.f, s2 = 0.f;
            for (int v = 0; v < 30; v++) {
                float ne = node_emb[v * 768 + c];
                s1 += c1[v] * ne;
                s2 += c2[v] * ne;
            }
            int h = c >> 6, d = c & 63;
            pe_s[h * 128 + d]      = f2b(s1);
            pe_s[h * 128 + 64 + d] = f2b(s2);
        }
        __syncthreads();
        int b = m >> 10, l = m & 1023;
        if (t < 192) {
            int h = t >> 4, ch = t & 15;     // 12 heads x 16 chunks of 8 u16 = KAUG 64..191
            u32x4 w = *reinterpret_cast<const u32x4*>(&pe_s[h * 128 + ch * 8]);
            size_t dst = ((size_t)(b * NH + h) * LL + l) * KAUG + 64 + ch * 8;
            *reinterpret_cast<u32x4*>(&Qa[dst]) = w;
            *reinterpret_cast<u32x4*>(&Ka[dst]) = w;
        }
    } else {
        // ---------------- dist pack: distance+1 -> u16
        int idx = ((lin - 4672) * 256 + tid) * 8;
        int4 a = *reinterpret_cast<const int4*>(&distance[idx]);
        int4 b = *reinterpret_cast<const int4*>(&distance[idx + 4]);
        u32x4 w;
        w[0] = (u32)(u16)(a.x + 1) | ((u32)(u16)(a.y + 1) << 16);
        w[1] = (u32)(u16)(a.z + 1) | ((u32)(u16)(a.w + 1) << 16);
        w[2] = (u32)(u16)(b.x + 1) | ((u32)(u16)(b.y + 1) << 16);
        w[3] = (u32)(u16)(b.z + 1) | ((u32)(u16)(b.w + 1) << 16);
        *reinterpret_cast<u32x4*>(&distu[idx]) = w;
    }
}

// ---------------------------------------------------------------- B: fused MFMA flash attention (i-split, LDS dbuf)
// v18 = r17 kernel + DOUBLE-BUFFERED K/V LDS. r16 isolated the bottleneck
// as the barrier/LDS serial chain (not load latency): the single-buffer
// scheme pays 2 barriers/tile with the dump fully exposed between them.
// Dbuf: load(t+1)->regs, compute(buf[t&1]), dump->buf[(t+1)&1], ONE
// barrier. End-of-iter barrier guarantees all compute(t) done before any
// wave dumps t+2 into buf[t&1]. LDS 79.9KB -> 2 blocks/CU = what we
// effectively measure today (occ 29% ~ 2.3), so occupancy cost ~nil
// while barrier count halves. Register layout unchanged (1-deep, r16-
// proven optimal).
__global__ __launch_bounds__(256, 2) void k_attn(const u16* __restrict__ Qa, const u16* __restrict__ Ka,
                                                 const u16* __restrict__ Vt,
                                                 const u16* __restrict__ distu,
                                                 const float* __restrict__ dist_emb,
                                                 const float* __restrict__ mask,
                                                 void* __restrict__ outv, int f32mode) {
    __shared__ __align__(16) u16 ka_s[2][64][200];   // 51200 B (row = 400 B, 16B-aligned)
    __shared__ __align__(16) u16 vt_s[2][64][80];    // 20480 B (row = 160 B, 16B-aligned)
    __shared__ float distcol[2048];                  // 8192 B  -> 79872 B total

    // XCD swizzle: xcd owns heads [6x,6x+6) (same batch per XCD pair) x 16 i-tiles
    int lin = blockIdx.x + (blockIdx.y << 4);     // gridDim (16,48), lin 0..767
    int xcd = lin & 7, slot = lin >> 3;           // slot 0..95
    int bh = xcd * 6 + (slot >> 4);               // 0..47, bijective
    int itile = slot & 15;                        // 0..15
    int b = bh / NH, h = bh % NH;
    int tid = threadIdx.x, wave = tid >> 6, lane = tid & 63, l15 = lane & 15, qd = lane >> 4;

    const u16* Qh = Qa + (size_t)bh * LL * KAUG;
    const u16* Kh = Ka + (size_t)bh * LL * KAUG;
    const u16* Vh = Vt + (size_t)bh * HD * LL;     // V^T: [d][1024], fp16
    const u16* distb = distu + (size_t)b * LL * LL;
    const float* maskb = mask + (size_t)b * LL;

    for (int t = tid; t < 2048; t += 256) distcol[t] = dist_emb[t * NH + h];

    int i0 = itile * 64 + wave * 16;
    bf16x8 aq[6];
#pragma unroll
    for (int ks = 0; ks < 6; ks++)
        aq[ks] = load8s(&Qh[(size_t)(i0 + l15) * KAUG + ks * 32 + qd * 8]);

    f32x4 o[4];
#pragma unroll
    for (int i = 0; i < 4; i++) o[i] = f32x4{0.f, 0.f, 0.f, 0.f};
    float m_i = -1e30f, l_i = 0.f;       // per-lane state for q-row i = l15

    u32x4 kbuf[6], vbuf[2];
    ushort4 dp[4];
    auto loadKV = [&](int j0) {
#pragma unroll
        for (int it = 0; it < 6; it++) {
            int c = tid + it * 256;
            int row = c / 24, col = (c % 24) * 8;
            kbuf[it] = *reinterpret_cast<const u32x4*>(&Kh[(size_t)(j0 + row) * KAUG + col]);
        }
#pragma unroll
        for (int it = 0; it < 2; it++) {
            int c = tid + it * 256;
            int d = c >> 3, col = (c & 7) * 8;
            vbuf[it] = *reinterpret_cast<const u32x4*>(&Vh[(size_t)d * LL + j0 + col]);
        }
    };
    auto dumpKV = [&](int buf) {
#pragma unroll
        for (int it = 0; it < 6; it++) {
            int c = tid + it * 256;
            int row = c / 24, col = (c % 24) * 8;
            *reinterpret_cast<u32x4*>(&ka_s[buf][row][col]) = kbuf[it];
        }
#pragma unroll
        for (int it = 0; it < 2; it++) {
            int c = tid + it * 256;
            int d = c >> 3, col = (c & 7) * 8;
            *reinterpret_cast<u32x4*>(&vt_s[buf][d][col]) = vbuf[it];
        }
    };

    // prologue: tile 0 -> buf0
    loadKV(0);
#pragma unroll
    for (int jf = 0; jf < 4; jf++)
        dp[jf] = *reinterpret_cast<const ushort4*>(&distb[(size_t)(i0 + l15) * LL + jf * 16 + qd * 4]);
    dumpKV(0);
    __syncthreads();

    for (int jt = 0; jt < 16; jt++) {
        int j0 = jt * 64;
        int cur = jt & 1;
        if (jt < 15) loadKV(j0 + 64);    // issue next tile's loads; land during compute

        // S^T = K * Q^T : lane holds S[i=l15][j = j0 + jf*16 + qd*4 + r]
        f32x4 st[4];
#pragma unroll
        for (int jf = 0; jf < 4; jf++) st[jf] = f32x4{0.f, 0.f, 0.f, 0.f};
        __builtin_amdgcn_s_setprio(1);
#pragma unroll
        for (int ks = 0; ks < 6; ks++) {
#pragma unroll
            for (int jf = 0; jf < 4; jf++) {
                bf16x8 ak = load8s(&ka_s[cur][jf * 16 + l15][ks * 32 + qd * 8]);
                st[jf] = __builtin_amdgcn_mfma_f32_16x16x32_bf16(ak, aq[ks], st[jf], 0, 0, 0);
            }
        }
        __builtin_amdgcn_s_setprio(0);
#pragma unroll
        for (int jf = 0; jf < 4; jf++) {
            float4 mk = *reinterpret_cast<const float4*>(&maskb[j0 + jf * 16 + qd * 4]);
            st[jf][0] += distcol[dp[jf].x] + mk.x;
            st[jf][1] += distcol[dp[jf].y] + mk.y;
            st[jf][2] += distcol[dp[jf].z] + mk.z;
            st[jf][3] += distcol[dp[jf].w] + mk.w;
        }
        if (jt < 15) {   // dist prefetch for next tile (issued AFTER use)
            int j0n = j0 + 64;
#pragma unroll
            for (int jf = 0; jf < 4; jf++)
                dp[jf] = *reinterpret_cast<const ushort4*>(&distb[(size_t)(i0 + l15) * LL + j0n + jf * 16 + qd * 4]);
        }

        float m0_ = fmaxf(fmaxf(st[0][0], st[0][1]), fmaxf(st[0][2], st[0][3]));
        float m1_ = fmaxf(fmaxf(st[1][0], st[1][1]), fmaxf(st[1][2], st[1][3]));
        float m2_ = fmaxf(fmaxf(st[2][0], st[2][1]), fmaxf(st[2][2], st[2][3]));
        float m3_ = fmaxf(fmaxf(st[3][0], st[3][1]), fmaxf(st[3][2], st[3][3]));
        float mx = fmaxf(fmaxf(m0_, m1_), fmaxf(m2_, m3_));
        mx = fmaxf(mx, __shfl_xor(mx, 16));
        mx = fmaxf(mx, __shfl_xor(mx, 32));
        if (!__all(mx <= m_i + 8.0f)) {          // defer-max
            float mnew = fmaxf(m_i, mx);
            float alpha = __expf(m_i - mnew);
            m_i = mnew;
            l_i *= alpha;
            float a0 = __shfl(alpha, qd * 4 + 0, 16);
            float a1 = __shfl(alpha, qd * 4 + 1, 16);
            float a2 = __shfl(alpha, qd * 4 + 2, 16);
            float a3 = __shfl(alpha, qd * 4 + 3, 16);
#pragma unroll
            for (int df = 0; df < 4; df++) {
                o[df][0] *= a0; o[df][1] *= a1; o[df][2] *= a2; o[df][3] *= a3;
            }
        }
        float ssum = 0.f;
        f16x4 pf[4];
#pragma unroll
        for (int jf = 0; jf < 4; jf++) {
            float p0 = __expf(st[jf][0] - m_i);
            float p1 = __expf(st[jf][1] - m_i);
            float p2 = __expf(st[jf][2] - m_i);
            float p3 = __expf(st[jf][3] - m_i);
            ssum += (p0 + p1) + (p2 + p3);
            pf[jf] = f16x4{(_Float16)p0, (_Float16)p1, (_Float16)p2, (_Float16)p3};
        }
        ssum += __shfl_xor(ssum, 16);
        ssum += __shfl_xor(ssum, 32);
        l_i += ssum;
        __builtin_amdgcn_s_setprio(1);
#pragma unroll
        for (int jf = 0; jf < 4; jf++) {
#pragma unroll
            for (int df = 0; df < 4; df++) {
                f16x4 vf = load4h(&vt_s[cur][df * 16 + l15][jf * 16 + qd * 4]);
                o[df] = __builtin_amdgcn_mfma_f32_16x16x16f16(pf[jf], vf, o[df], 0, 0, 0);
            }
        }
        __builtin_amdgcn_s_setprio(0);

        if (jt < 15) {
            dumpKV(cur ^ 1);             // write next tile into the idle buffer
            __syncthreads();             // ONE barrier per tile
        }
    }

    // direct epilogue: normalize and write d_out
    float lr0 = 1.f / __shfl(l_i, qd * 4 + 0, 16);
    float lr1 = 1.f / __shfl(l_i, qd * 4 + 1, 16);
    float lr2 = 1.f / __shfl(l_i, qd * 4 + 2, 16);
    float lr3 = 1.f / __shfl(l_i, qd * 4 + 3, 16);
#pragma unroll
    for (int df = 0; df < 4; df++) {
        int d = df * 16 + l15;
        float v0 = o[df][0] * lr0, v1 = o[df][1] * lr1, v2 = o[df][2] * lr2, v3 = o[df][3] * lr3;
        int i_abs = i0 + qd * 4;
        size_t idx = ((size_t)(b * LL) + i_abs) * HID + h * 64 + d;
        if (f32mode) {
            float* op = (float*)outv;
            op[idx] = v0; op[idx + HID] = v1; op[idx + 2 * HID] = v2; op[idx + 3 * HID] = v3;
        } else {
            u16* op = (u16*)outv;
            op[idx] = f2b(v0); op[idx + HID] = f2b(v1); op[idx + 2 * HID] = f2b(v2); op[idx + 3 * HID] = f2b(v3);
        }
    }
}

// ---------------------------------------------------------------- launch
extern "C" void kernel_launch(void* const* d_in, const int* in_sizes, int n_in,
                              void* d_out, int out_size, void* d_ws, size_t ws_size,
                              hipStream_t stream) {
    const float* hs       = (const float*)d_in[0];
    const float* mask     = (const float*)d_in[1];
    const float* Wq       = (const float*)d_in[2];
    const float* bq       = (const float*)d_in[3];
    const float* Wk       = (const float*)d_in[4];
    const float* bk       = (const float*)d_in[5];
    const float* Wv       = (const float*)d_in[6];
    const float* bv       = (const float*)d_in[7];
    const float* node_emb = (const float*)d_in[8];
    const float* dist_emb = (const float*)d_in[9];
    const int* distance   = (const int*)d_in[10];
    const int* rw         = (const int*)d_in[11];
    const int* arw        = (const int*)d_in[12];

    int f32mode = 0;
    {
        hipDeviceptr_t base = nullptr; size_t sz = 0;
        if (hipMemGetAddressRange(&base, &sz, (hipDeviceptr_t)d_out) == hipSuccess) {
            size_t off = (size_t)((char*)d_out - (char*)base);
            if (sz - off >= (size_t)out_size * 4u) f32mode = 1;
        }
    }

    u16* Qa = (u16*)d_ws;                            // 48*1024*192 bf16   (18.9 MB)
    u16* Ka = Qa + (size_t)NBH * LL * KAUG;          // 18.9 MB
    u16* Vt = Ka + (size_t)NBH * LL * KAUG;          // V^T fp16, 6.3 MB
    u16* distu = Vt + (size_t)NBH * HD * LL;         // 8.4 MB
    u16* hs16 = distu + (size_t)4 * LL * LL;         // 6.3 MB
    u16* w16  = hs16 + (size_t)4096 * 768;           // 3.5 MB

    k_pre<<<dim3(2400), dim3(256), 0, stream>>>(hs, Wq, Wk, Wv, hs16, w16);
    k_qkvpe<<<dim3(6720), dim3(256), 0, stream>>>(hs16, w16, bq, bk, bv, rw, arw, node_emb,
                                                  distance, Qa, Ka, Vt, distu);
    k_attn<<<dim3(16, 48), dim3(256), 0, stream>>>(Qa, Ka, Vt, distu, dist_emb, mask, d_out, f32mode);
}

// Round 19
// 214.388 us; speedup vs baseline: 1.0276x; 1.0276x over previous
//
#include <hip/hip_runtime.h>
#include <hip/hip_bf16.h>

#define LL 1024
#define HID 768
#define NH 12
#define HD 64
#define KAUG 192   // 64 (q/8 or k) + 64 e1 + 64 e2
#define NBH 48     // B*NH

typedef unsigned int u32;
typedef unsigned short u16;
typedef __bf16 bf16_t;
typedef bf16_t bf16x8 __attribute__((ext_vector_type(8)));
typedef _Float16 f16x4 __attribute__((ext_vector_type(4)));
typedef float f32x4 __attribute__((ext_vector_type(4)));
typedef u32 u32x4 __attribute__((ext_vector_type(4)));

__device__ __forceinline__ u16 f2b(float f) {
    union { float f; u32 u; } v; v.f = f;
    u32 r = v.u + 0x7fffu + ((v.u >> 16) & 1u);
    return (u16)(r >> 16);
}
__device__ __forceinline__ u16 f2h(float f) {
    _Float16 h = (_Float16)f;
    return __builtin_bit_cast(u16, h);
}
__device__ __forceinline__ bf16x8 load8s(const u16* p) {  // LDS/global, 16B aligned
    return __builtin_bit_cast(bf16x8, *reinterpret_cast<const u32x4*>(p));
}
__device__ __forceinline__ f16x4 load4h(const u16* p) {   // LDS, 8B aligned
    return __builtin_bit_cast(f16x4, *reinterpret_cast<const unsigned long long*>(p));
}
__device__ __forceinline__ void cvt4_store_v(u16* dst, float4 f) {
    ushort4 o;
    o.x = f2b(f.x); o.y = f2b(f.y); o.z = f2b(f.z); o.w = f2b(f.w);
    *reinterpret_cast<ushort4*>(dst) = o;
}

// ---------------------------------------------------------------- A0: f32 -> bf16 cvt (hs [0,1536) | W [1536,2400))
__global__ __launch_bounds__(256) void k_pre(const float* __restrict__ hs,
                                             const float* __restrict__ Wq, const float* __restrict__ Wk,
                                             const float* __restrict__ Wv,
                                             u16* __restrict__ hs16, u16* __restrict__ w16) {
    int bx = blockIdx.x;
    const float* src; u16* dst; int base;
    if (bx < 1536) { src = hs; dst = hs16; base = bx; }
    else {
        int w = bx - 1536;               // 0..863
        int which = w / 288;             // 0=q 1=k 2=v
        src = (which == 0) ? Wq : (which == 1) ? Wk : Wv;
        dst = w16 + (size_t)which * 768 * 768;
        base = w - which * 288;
    }
    int idx = (base * 256 + threadIdx.x) * 8;
    float4 a = *reinterpret_cast<const float4*>(&src[idx]);
    float4 b = *reinterpret_cast<const float4*>(&src[idx + 4]);
    cvt4_store_v(&dst[idx], a);
    cvt4_store_v(&dst[idx + 4], b);
}

// ---------------------------------------------------------------- A2+A3+A1 fused: QKV + walk-PE + dist-pack
// segments: [0,576) qkv MFMA blocks (dispatch first) | [576,4672) pe |
// [4672,6720) dist pack. All outputs disjoint; pe/pack soak up CUs while
// qkv blocks wait on memory (r14: fusion gained ~32us).
__global__ __launch_bounds__(256) void k_qkvpe(const u16* __restrict__ hs16,
                                               const u16* __restrict__ w16,
                                               const float* __restrict__ bq, const float* __restrict__ bk,
                                               const float* __restrict__ bv,
                                               const int* __restrict__ rw, const int* __restrict__ arw,
                                               const float* __restrict__ node_emb,
                                               const int* __restrict__ distance,
                                               u16* __restrict__ Qa, u16* __restrict__ Ka,
                                               u16* __restrict__ Vt, u16* __restrict__ distu) {
    __shared__ __align__(16) u16 smem[18432];
    int lin = blockIdx.x;
    int tid = threadIdx.x;
    if (lin < 576) {
        // ---------------- QKV path (XCD-affine: xcd owns m-tiles [4x,4x+4) x all nt)
        u16* a_s = smem;                 // [row][col] stride 72
        u16* b_s = smem + 9216;
        int xcd = lin & 7, idx = lin >> 3;          // idx 0..71
        int mt = xcd * 4 + (idx & 3);               // 0..31
        int nt = idx >> 2;                          // 0..17
        int m0 = mt * 128;
        int which = nt / 6;                  // 0=q 1=k 2=v
        int n0w = (nt % 6) * 128;
        const u16* W = w16 + (size_t)which * 768 * 768;
        const float* bias = (which == 0) ? bq : (which == 1) ? bk : bv;
        int wave = tid >> 6, lane = tid & 63, l15 = lane & 15, qd = lane >> 4;
        int wm = wave >> 1, wn = wave & 1;
        int srow = tid >> 3, scol = (tid & 7) * 8;

        f32x4 acc[4][4];
        for (int i = 0; i < 4; i++)
            for (int j = 0; j < 4; j++) acc[i][j] = f32x4{0.f, 0.f, 0.f, 0.f};

        u32x4 pa[4], pb[4];
#pragma unroll
        for (int it = 0; it < 4; it++) {
            int row = srow + it * 32;
            pa[it] = *reinterpret_cast<const u32x4*>(&hs16[(size_t)(m0 + row) * 768 + scol]);
            pb[it] = *reinterpret_cast<const u32x4*>(&W[(size_t)(n0w + row) * 768 + scol]);
        }
        for (int k0 = 0; k0 < 768; k0 += 64) {
            __syncthreads();
#pragma unroll
            for (int it = 0; it < 4; it++) {
                int row = srow + it * 32;
                *reinterpret_cast<u32x4*>(&a_s[row * 72 + scol]) = pa[it];
                *reinterpret_cast<u32x4*>(&b_s[row * 72 + scol]) = pb[it];
            }
            __syncthreads();
            if (k0 < 704) {
                int k1 = k0 + 64;
#pragma unroll
                for (int it = 0; it < 4; it++) {
                    int row = srow + it * 32;
                    pa[it] = *reinterpret_cast<const u32x4*>(&hs16[(size_t)(m0 + row) * 768 + k1 + scol]);
                    pb[it] = *reinterpret_cast<const u32x4*>(&W[(size_t)(n0w + row) * 768 + k1 + scol]);
                }
            }
            for (int kk = 0; kk < 2; kk++) {
                bf16x8 af[4], bf[4];
                for (int i = 0; i < 4; i++) af[i] = load8s(&a_s[(wm * 64 + i * 16 + l15) * 72 + kk * 32 + qd * 8]);
                for (int j = 0; j < 4; j++) bf[j] = load8s(&b_s[(wn * 64 + j * 16 + l15) * 72 + kk * 32 + qd * 8]);
                for (int i = 0; i < 4; i++)
                    for (int j = 0; j < 4; j++)
                        acc[i][j] = __builtin_amdgcn_mfma_f32_16x16x32_bf16(af[i], bf[j], acc[i][j], 0, 0, 0);
            }
        }
        __syncthreads();
        int b = m0 >> 10, l0b = m0 & 1023;
        if (which != 2) {
            float qscale = (which == 0) ? 0.125f : 1.0f;
            for (int i = 0; i < 4; i++) {
                int m_loc = wm * 64 + i * 16 + qd * 4;
                for (int j = 0; j < 4; j++) {
                    int n_loc = wn * 64 + j * 16 + l15;
                    float bv_ = bias[n0w + n_loc];
                    for (int r = 0; r < 4; r++)
                        smem[(m_loc + r) * 136 + n_loc] = f2b((acc[i][j][r] + bv_) * qscale);
                }
            }
            __syncthreads();
            u16* dstbuf = (which == 0) ? Qa : Ka;
            for (int it = 0; it < 8; it++) {
                int c = tid + it * 256;
                int row = c >> 4, col = (c & 15) * 8;
                u32x4 w = *reinterpret_cast<u32x4*>(&smem[row * 136 + col]);
                int nn = n0w + col;
                int h = nn >> 6, d = nn & 63;
                size_t dst = ((size_t)(b * NH + h) * LL + (l0b + row)) * KAUG + d;
                *reinterpret_cast<u32x4*>(&dstbuf[dst]) = w;
            }
        } else {
            // V stored as FP16 (feeds the 16x16x16 f16 PV MFMA in k_attn)
            for (int i = 0; i < 4; i++) {
                int m_loc = wm * 64 + i * 16 + qd * 4;
                for (int j = 0; j < 4; j++) {
                    int n_loc = wn * 64 + j * 16 + l15;
                    float bv_ = bias[n0w + n_loc];
                    for (int r = 0; r < 4; r++)
                        smem[n_loc * 136 + (m_loc + r)] = f2h(acc[i][j][r] + bv_);
                }
            }
            __syncthreads();
            for (int it = 0; it < 8; it++) {
                int c = tid + it * 256;
                int n = c >> 4, m_off = (c & 15) * 8;
                u32x4 w = *reinterpret_cast<u32x4*>(&smem[n * 136 + m_off]);
                int nn = n0w + n;
                int h = nn >> 6, d = nn & 63;
                size_t dst = ((size_t)(b * NH + h) * HD + d) * LL + (l0b + m_off);
                *reinterpret_cast<u32x4*>(&Vt[dst]) = w;
            }
        }
    } else if (lin < 4672) {
        // ---------------- PE path: histogram + counts @ node_emb
        int m = lin - 576;                   // b*L + l, 0..4095
        int* hist = (int*)smem;              // 64 ints @ byte 0
        float* c1 = (float*)(smem + 128);    // 32 f @ byte 256
        float* c2 = (float*)(smem + 192);    // 32 f @ byte 384
        u16* pe_s = smem + 256;              // 1536 u16 @ byte 512
        int t = tid;
        if (t < 64) hist[t] = 0;
        __syncthreads();
        if (t < 128) atomicAdd(&hist[rw[m * 128 + t] & 31], 1);
        else         atomicAdd(&hist[32 + (arw[m * 128 + (t - 128)] & 31)], 1);
        __syncthreads();
        if (t < 64) {
            if (t < 32) c1[t] = (float)hist[t];
            else        c2[t - 32] = (float)hist[t];
        }
        __syncthreads();
        for (int c = t; c < 768; c += 256) {
            float s1 = 0.f, s2 = 0.f;
            for (int v = 0; v < 30; v++) {
                float ne = node_emb[v * 768 + c];
                s1 += c1[v] * ne;
                s2 += c2[v] * ne;
            }
            int h = c >> 6, d = c & 63;
            pe_s[h * 128 + d]      = f2b(s1);
            pe_s[h * 128 + 64 + d] = f2b(s2);
        }
        __syncthreads();
        int b = m >> 10, l = m & 1023;
        if (t < 192) {
            int h = t >> 4, ch = t & 15;     // 12 heads x 16 chunks of 8 u16 = KAUG 64..191
            u32x4 w = *reinterpret_cast<const u32x4*>(&pe_s[h * 128 + ch * 8]);
            size_t dst = ((size_t)(b * NH + h) * LL + l) * KAUG + 64 + ch * 8;
            *reinterpret_cast<u32x4*>(&Qa[dst]) = w;
            *reinterpret_cast<u32x4*>(&Ka[dst]) = w;
        }
    } else {
        // ---------------- dist pack: distance+1 -> u16
        int idx = ((lin - 4672) * 256 + tid) * 8;
        int4 a = *reinterpret_cast<const int4*>(&distance[idx]);
        int4 b = *reinterpret_cast<const int4*>(&distance[idx + 4]);
        u32x4 w;
        w[0] = (u32)(u16)(a.x + 1) | ((u32)(u16)(a.y + 1) << 16);
        w[1] = (u32)(u16)(a.z + 1) | ((u32)(u16)(a.w + 1) << 16);
        w[2] = (u32)(u16)(b.x + 1) | ((u32)(u16)(b.y + 1) << 16);
        w[3] = (u32)(u16)(b.z + 1) | ((u32)(u16)(b.w + 1) << 16);
        *reinterpret_cast<u32x4*>(&distu[idx]) = w;
    }
}

// ---------------------------------------------------------------- B: fused MFMA flash attention (i-split, direct out)
// v19 = exact r17/r15 kernel — the measured optimum. All structural axes
// bracketed by experiment: 768 blocks i-split (r8/r15), 1-deep prefetch
// (r16: 2-deep regressed), 2-barrier single-buffer (r18: dbuf regressed,
// occupancy 29->17.6% outweighed barrier halving), 16B-aligned LDS rows
// (r9: padding poison), XCD head-affinity (r12: FETCH 113.6->30.2MB),
// direct d_out write (r15: partials+comb removed). Latency-bound plateau:
// MfmaUtil ~15%, HBM ~6.5%, FETCH ~= compulsory.
__global__ __launch_bounds__(256, 2) void k_attn(const u16* __restrict__ Qa, const u16* __restrict__ Ka,
                                                 const u16* __restrict__ Vt,
                                                 const u16* __restrict__ distu,
                                                 const float* __restrict__ dist_emb,
                                                 const float* __restrict__ mask,
                                                 void* __restrict__ outv, int f32mode) {
    __shared__ __align__(16) u16 ka_s[64][200];   // 25600 B (row = 400 B, 16B-aligned)
    __shared__ __align__(16) u16 vt_s[64][80];    // 10240 B (row = 160 B, 16B-aligned)
    __shared__ float distcol[2048];               // 8192 B

    // XCD swizzle: xcd owns heads [6x,6x+6) (same batch per XCD pair) x 16 i-tiles
    int lin = blockIdx.x + (blockIdx.y << 4);     // gridDim (16,48), lin 0..767
    int xcd = lin & 7, slot = lin >> 3;           // slot 0..95
    int bh = xcd * 6 + (slot >> 4);               // 0..47, bijective
    int itile = slot & 15;                        // 0..15
    int b = bh / NH, h = bh % NH;
    int tid = threadIdx.x, wave = tid >> 6, lane = tid & 63, l15 = lane & 15, qd = lane >> 4;

    const u16* Qh = Qa + (size_t)bh * LL * KAUG;
    const u16* Kh = Ka + (size_t)bh * LL * KAUG;
    const u16* Vh = Vt + (size_t)bh * HD * LL;     // V^T: [d][1024], fp16
    const u16* distb = distu + (size_t)b * LL * LL;
    const float* maskb = mask + (size_t)b * LL;

    for (int t = tid; t < 2048; t += 256) distcol[t] = dist_emb[t * NH + h];

    int i0 = itile * 64 + wave * 16;
    bf16x8 aq[6];
#pragma unroll
    for (int ks = 0; ks < 6; ks++)
        aq[ks] = load8s(&Qh[(size_t)(i0 + l15) * KAUG + ks * 32 + qd * 8]);

    f32x4 o[4];
#pragma unroll
    for (int i = 0; i < 4; i++) o[i] = f32x4{0.f, 0.f, 0.f, 0.f};
    float m_i = -1e30f, l_i = 0.f;       // per-lane state for q-row i = l15

    // ---- register prefetch: K/V tile 0 + dist tile 0
    u32x4 kbuf[6], vbuf[2];
    ushort4 dp[4];
#pragma unroll
    for (int it = 0; it < 6; it++) {
        int c = tid + it * 256;
        int row = c / 24, col = (c % 24) * 8;
        kbuf[it] = *reinterpret_cast<const u32x4*>(&Kh[(size_t)row * KAUG + col]);
    }
#pragma unroll
    for (int it = 0; it < 2; it++) {
        int c = tid + it * 256;
        int d = c >> 3, col = (c & 7) * 8;
        vbuf[it] = *reinterpret_cast<const u32x4*>(&Vh[(size_t)d * LL + col]);
    }
#pragma unroll
    for (int jf = 0; jf < 4; jf++)
        dp[jf] = *reinterpret_cast<const ushort4*>(&distb[(size_t)(i0 + l15) * LL + jf * 16 + qd * 4]);

    for (int jt = 0; jt < 16; jt++) {
        int j0 = jt * 64;
        __syncthreads();                 // prior tile's LDS reads done
#pragma unroll
        for (int it = 0; it < 6; it++) {
            int c = tid + it * 256;
            int row = c / 24, col = (c % 24) * 8;
            *reinterpret_cast<u32x4*>(&ka_s[row][col]) = kbuf[it];
        }
#pragma unroll
        for (int it = 0; it < 2; it++) {
            int c = tid + it * 256;
            int d = c >> 3, col = (c & 7) * 8;
            *reinterpret_cast<u32x4*>(&vt_s[d][col]) = vbuf[it];
        }
        __syncthreads();
        if (jt < 15) {                   // next tile's K/V; consumed at next dump
            int j0n = j0 + 64;
#pragma unroll
            for (int it = 0; it < 6; it++) {
                int c = tid + it * 256;
                int row = c / 24, col = (c % 24) * 8;
                kbuf[it] = *reinterpret_cast<const u32x4*>(&Kh[(size_t)(j0n + row) * KAUG + col]);
            }
#pragma unroll
            for (int it = 0; it < 2; it++) {
                int c = tid + it * 256;
                int d = c >> 3, col = (c & 7) * 8;
                vbuf[it] = *reinterpret_cast<const u32x4*>(&Vh[(size_t)d * LL + j0n + col]);
            }
        }

        // S^T = K * Q^T : lane holds S[i=l15][j = j0 + jf*16 + qd*4 + r]
        f32x4 st[4];
#pragma unroll
        for (int jf = 0; jf < 4; jf++) st[jf] = f32x4{0.f, 0.f, 0.f, 0.f};
        __builtin_amdgcn_s_setprio(1);
#pragma unroll
        for (int ks = 0; ks < 6; ks++) {
#pragma unroll
            for (int jf = 0; jf < 4; jf++) {
                bf16x8 ak = load8s(&ka_s[jf * 16 + l15][ks * 32 + qd * 8]);
                st[jf] = __builtin_amdgcn_mfma_f32_16x16x32_bf16(ak, aq[ks], st[jf], 0, 0, 0);
            }
        }
        __builtin_amdgcn_s_setprio(0);
#pragma unroll
        for (int jf = 0; jf < 4; jf++) {
            float4 mk = *reinterpret_cast<const float4*>(&maskb[j0 + jf * 16 + qd * 4]);
            st[jf][0] += distcol[dp[jf].x] + mk.x;
            st[jf][1] += distcol[dp[jf].y] + mk.y;
            st[jf][2] += distcol[dp[jf].z] + mk.z;
            st[jf][3] += distcol[dp[jf].w] + mk.w;
        }
        if (jt < 15) {   // dist prefetch for next tile (issued AFTER use)
            int j0n = j0 + 64;
#pragma unroll
            for (int jf = 0; jf < 4; jf++)
                dp[jf] = *reinterpret_cast<const ushort4*>(&distb[(size_t)(i0 + l15) * LL + j0n + jf * 16 + qd * 4]);
        }

        float m0_ = fmaxf(fmaxf(st[0][0], st[0][1]), fmaxf(st[0][2], st[0][3]));
        float m1_ = fmaxf(fmaxf(st[1][0], st[1][1]), fmaxf(st[1][2], st[1][3]));
        float m2_ = fmaxf(fmaxf(st[2][0], st[2][1]), fmaxf(st[2][2], st[2][3]));
        float m3_ = fmaxf(fmaxf(st[3][0], st[3][1]), fmaxf(st[3][2], st[3][3]));
        float mx = fmaxf(fmaxf(m0_, m1_), fmaxf(m2_, m3_));
        mx = fmaxf(mx, __shfl_xor(mx, 16));
        mx = fmaxf(mx, __shfl_xor(mx, 32));
        if (!__all(mx <= m_i + 8.0f)) {          // defer-max
            float mnew = fmaxf(m_i, mx);
            float alpha = __expf(m_i - mnew);
            m_i = mnew;
            l_i *= alpha;
            float a0 = __shfl(alpha, qd * 4 + 0, 16);
            float a1 = __shfl(alpha, qd * 4 + 1, 16);
            float a2 = __shfl(alpha, qd * 4 + 2, 16);
            float a3 = __shfl(alpha, qd * 4 + 3, 16);
#pragma unroll
            for (int df = 0; df < 4; df++) {
                o[df][0] *= a0; o[df][1] *= a1; o[df][2] *= a2; o[df][3] *= a3;
            }
        }
        float ssum = 0.f;
        f16x4 pf[4];
#pragma unroll
        for (int jf = 0; jf < 4; jf++) {
            float p0 = __expf(st[jf][0] - m_i);
            float p1 = __expf(st[jf][1] - m_i);
            float p2 = __expf(st[jf][2] - m_i);
            float p3 = __expf(st[jf][3] - m_i);
            ssum += (p0 + p1) + (p2 + p3);
            pf[jf] = f16x4{(_Float16)p0, (_Float16)p1, (_Float16)p2, (_Float16)p3};
        }
        ssum += __shfl_xor(ssum, 16);
        ssum += __shfl_xor(ssum, 32);
        l_i += ssum;
        __builtin_amdgcn_s_setprio(1);
#pragma unroll
        for (int jf = 0; jf < 4; jf++) {
#pragma unroll
            for (int df = 0; df < 4; df++) {
                f16x4 vf = load4h(&vt_s[df * 16 + l15][jf * 16 + qd * 4]);
                o[df] = __builtin_amdgcn_mfma_f32_16x16x16f16(pf[jf], vf, o[df], 0, 0, 0);
            }
        }
        __builtin_amdgcn_s_setprio(0);
    }

    // direct epilogue: normalize and write d_out
    float lr0 = 1.f / __shfl(l_i, qd * 4 + 0, 16);
    float lr1 = 1.f / __shfl(l_i, qd * 4 + 1, 16);
    float lr2 = 1.f / __shfl(l_i, qd * 4 + 2, 16);
    float lr3 = 1.f / __shfl(l_i, qd * 4 + 3, 16);
#pragma unroll
    for (int df = 0; df < 4; df++) {
        int d = df * 16 + l15;
        float v0 = o[df][0] * lr0, v1 = o[df][1] * lr1, v2 = o[df][2] * lr2, v3 = o[df][3] * lr3;
        int i_abs = i0 + qd * 4;
        size_t idx = ((size_t)(b * LL) + i_abs) * HID + h * 64 + d;
        if (f32mode) {
            float* op = (float*)outv;
            op[idx] = v0; op[idx + HID] = v1; op[idx + 2 * HID] = v2; op[idx + 3 * HID] = v3;
        } else {
            u16* op = (u16*)outv;
            op[idx] = f2b(v0); op[idx + HID] = f2b(v1); op[idx + 2 * HID] = f2b(v2); op[idx + 3 * HID] = f2b(v3);
        }
    }
}

// ---------------------------------------------------------------- launch
extern "C" void kernel_launch(void* const* d_in, const int* in_sizes, int n_in,
                              void* d_out, int out_size, void* d_ws, size_t ws_size,
                              hipStream_t stream) {
    const float* hs       = (const float*)d_in[0];
    const float* mask     = (const float*)d_in[1];
    const float* Wq       = (const float*)d_in[2];
    const float* bq       = (const float*)d_in[3];
    const float* Wk       = (const float*)d_in[4];
    const float* bk       = (const float*)d_in[5];
    const float* Wv       = (const float*)d_in[6];
    const float* bv       = (const float*)d_in[7];
    const float* node_emb = (const float*)d_in[8];
    const float* dist_emb = (const float*)d_in[9];
    const int* distance   = (const int*)d_in[10];
    const int* rw         = (const int*)d_in[11];
    const int* arw        = (const int*)d_in[12];

    int f32mode = 0;
    {
        hipDeviceptr_t base = nullptr; size_t sz = 0;
        if (hipMemGetAddressRange(&base, &sz, (hipDeviceptr_t)d_out) == hipSuccess) {
            size_t off = (size_t)((char*)d_out - (char*)base);
            if (sz - off >= (size_t)out_size * 4u) f32mode = 1;
        }
    }

    u16* Qa = (u16*)d_ws;                            // 48*1024*192 bf16   (18.9 MB)
    u16* Ka = Qa + (size_t)NBH * LL * KAUG;          // 18.9 MB
    u16* Vt = Ka + (size_t)NBH * LL * KAUG;          // V^T fp16, 6.3 MB
    u16* distu = Vt + (size_t)NBH * HD * LL;         // 8.4 MB
    u16* hs16 = distu + (size_t)4 * LL * LL;         // 6.3 MB
    u16* w16  = hs16 + (size_t)4096 * 768;           // 3.5 MB

    k_pre<<<dim3(2400), dim3(256), 0, stream>>>(hs, Wq, Wk, Wv, hs16, w16);
    k_qkvpe<<<dim3(6720), dim3(256), 0, stream>>>(hs16, w16, bq, bk, bv, rw, arw, node_emb,
                                                  distance, Qa, Ka, Vt, distu);
    k_attn<<<dim3(16, 48), dim3(256), 0, stream>>>(Qa, Ka, Vt, distu, dist_emb, mask, d_out, f32mode);
}